// Round 1
// baseline (1270.098 us; speedup 1.0000x reference)
//
#include <hip/hip_runtime.h>
#include <math.h>

#define HW 2304
#define EPSV 1e-5f
#define ATT_SCALE 0.17677669529663687f  // 32^-0.5

enum { EPI_BNSILU = 0, EPI_BIAS = 1, EPI_BIAS_GELU = 2, EPI_BIAS_RES = 3 };

// Y[b][o][n] = epi( sum_c W[o][c] * X[b][c][n] )
// 64x64 output tile per block, 256 threads, 4x4 micro-tile, K-tile 16.
template <int EPI>
__global__ __launch_bounds__(256) void gemm_f32(
    const float* __restrict__ W, const float* __restrict__ X,
    float* __restrict__ Y, int C, long sxb, long syb,
    const float* __restrict__ p0, const float* __restrict__ p1,
    const float* __restrict__ p2, const float* __restrict__ p3,
    const float* __restrict__ R, long srb)
{
    __shared__ float As[16][68];  // [k][o], padded
    __shared__ float Bs[16][64];  // [k][n]
    const int b  = blockIdx.z;
    const int ob = blockIdx.y * 64;
    const int nb = blockIdx.x * 64;
    const float* Xb = X + (size_t)b * sxb;
    const int t  = threadIdx.x;
    const int tx = t & 15, ty = t >> 4;
    const int wo = t >> 2, wk = (t & 3) * 4;
    const int xk = t >> 4, xn = (t & 15) * 4;

    float acc[4][4] = {};
    float4 wv = *(const float4*)&W[(size_t)(ob + wo) * C + wk];
    float4 xv = *(const float4*)&Xb[(size_t)xk * HW + nb + xn];

    for (int c0 = 0; c0 < C; c0 += 16) {
        __syncthreads();
        As[wk + 0][wo] = wv.x; As[wk + 1][wo] = wv.y;
        As[wk + 2][wo] = wv.z; As[wk + 3][wo] = wv.w;
        *(float4*)&Bs[xk][xn] = xv;
        __syncthreads();
        if (c0 + 16 < C) {
            wv = *(const float4*)&W[(size_t)(ob + wo) * C + c0 + 16 + wk];
            xv = *(const float4*)&Xb[(size_t)(c0 + 16 + xk) * HW + nb + xn];
        }
        #pragma unroll
        for (int k = 0; k < 16; k++) {
            float4 bv4 = *(const float4*)&Bs[k][tx * 4];
            float bj[4] = {bv4.x, bv4.y, bv4.z, bv4.w};
            float ai[4];
            #pragma unroll
            for (int i = 0; i < 4; i++) ai[i] = As[k][ty * 4 + i];
            #pragma unroll
            for (int i = 0; i < 4; i++)
                #pragma unroll
                for (int j = 0; j < 4; j++)
                    acc[i][j] = fmaf(ai[i], bj[j], acc[i][j]);
        }
    }

    #pragma unroll
    for (int i = 0; i < 4; i++) {
        const int o = ob + ty * 4 + i;
        float scale = 1.f, shift;
        if (EPI == EPI_BNSILU) {
            const float rs = rsqrtf(p3[o] + EPSV);
            scale = p0[o] * rs;
            shift = p1[o] - p2[o] * scale;
        } else {
            shift = p0[o];
        }
        float rv[4];
        if (EPI == EPI_BIAS_RES)
            *(float4*)rv = *(const float4*)&R[(size_t)b * srb + (size_t)o * HW + nb + tx * 4];
        float ov[4];
        #pragma unroll
        for (int j = 0; j < 4; j++) {
            float v = fmaf(acc[i][j], scale, shift);
            if (EPI == EPI_BNSILU)         v = v / (1.f + __expf(-v));
            else if (EPI == EPI_BIAS_GELU) v = 0.5f * v * (1.f + erff(v * 0.70710678f));
            else if (EPI == EPI_BIAS_RES)  v += rv[j];
            ov[j] = v;
        }
        *(float4*)&Y[(size_t)b * syb + (size_t)o * HW + nb + tx * 4] = *(float4*)ov;
    }
}

// GroupNorm(num_groups=1) over 128*HW elems per batch: partial -> reduce -> apply
__global__ __launch_bounds__(256) void gn_partial(
    const float* __restrict__ X, long sxb, float* __restrict__ stats)
{
    const int b = blockIdx.y;
    const float* xb = X + (size_t)b * sxb + (size_t)blockIdx.x * 6144;
    float s = 0.f, sq = 0.f;
    #pragma unroll
    for (int k = 0; k < 6; k++) {
        float4 v = *(const float4*)&xb[(size_t)(k * 256 + threadIdx.x) * 4];
        s  += v.x + v.y + v.z + v.w;
        sq += v.x * v.x + v.y * v.y + v.z * v.z + v.w * v.w;
    }
    #pragma unroll
    for (int off = 32; off; off >>= 1) { s += __shfl_xor(s, off); sq += __shfl_xor(sq, off); }
    __shared__ float ps[4], pq[4];
    const int wave = threadIdx.x >> 6, lane = threadIdx.x & 63;
    if (lane == 0) { ps[wave] = s; pq[wave] = sq; }
    __syncthreads();
    if (threadIdx.x == 0) {
        stats[b * 48 + blockIdx.x]       = ps[0] + ps[1] + ps[2] + ps[3];
        stats[144 + b * 48 + blockIdx.x] = pq[0] + pq[1] + pq[2] + pq[3];
    }
}

__global__ void gn_reduce(float* __restrict__ stats)
{
    const int b = blockIdx.x, t = threadIdx.x;  // 64 threads
    float s  = (t < 48) ? stats[b * 48 + t] : 0.f;
    float sq = (t < 48) ? stats[144 + b * 48 + t] : 0.f;
    #pragma unroll
    for (int off = 32; off; off >>= 1) { s += __shfl_xor(s, off); sq += __shfl_xor(sq, off); }
    if (t == 0) {
        const float inv = 1.f / 294912.f;
        const float mean = s * inv;
        const float var  = sq * inv - mean * mean;
        stats[288 + b] = mean;
        stats[292 + b] = rsqrtf(var + EPSV);
    }
}

__global__ __launch_bounds__(256) void gn_apply(
    const float* __restrict__ X, long sxb, float* __restrict__ Z, long szb,
    const float* __restrict__ g, const float* __restrict__ bb,
    const float* __restrict__ stats)
{
    const int b = blockIdx.y;
    const float mean = stats[288 + b];
    const float rs   = stats[292 + b];
    const float* xb = X + (size_t)b * sxb;
    float* zb = Z + (size_t)b * szb;
    #pragma unroll
    for (int k = 0; k < 4; k++) {
        const int v4 = blockIdx.x * 1024 + k * 256 + threadIdx.x;
        const int c  = v4 / 576;  // HW/4 = 576 float4 per channel
        const float sc = rs * g[c];
        const float sh = bb[c] - mean * sc;
        float4 v = *(const float4*)&xb[(size_t)v4 * 4];
        v.x = fmaf(v.x, sc, sh); v.y = fmaf(v.y, sc, sh);
        v.z = fmaf(v.z, sc, sh); v.w = fmaf(v.w, sc, sh);
        *(float4*)&zb[(size_t)v4 * 4] = v;
    }
}

// Flash attention over the reference's cross-batch quirk:
// Q = qkv[batch0], K = qkv[batch1], V = qkv[batch2]; 12 (j,h) pairs, N=M=2304, D=32.
// One wave per query n; block = 4 waves sharing LDS-staged K/V tiles of 64 m.
// Output channel layout: ao[j][(d*4+h)][n].
__global__ __launch_bounds__(256) void flash_attn(
    const float* __restrict__ qkv, float* __restrict__ ao)
{
    __shared__ float Ks[32][64];
    __shared__ float Vs[32][64];
    const int jh = blockIdx.y, j = jh >> 2, h = jh & 3;
    const float* Q = qkv + (size_t)(j * 128 + h * 32) * HW;
    const float* K = Q + (size_t)384 * HW;
    const float* V = K + (size_t)384 * HW;
    const int t = threadIdx.x, wave = t >> 6, lane = t & 63;
    const int n = blockIdx.x * 4 + wave;

    float q[32], O[32];
    #pragma unroll
    for (int d = 0; d < 32; d++) { q[d] = Q[(size_t)d * HW + n] * ATT_SCALE; O[d] = 0.f; }
    float M = -3.0e38f, S = 0.f;

    const int ld = t >> 3;        // 0..31 (d row this thread stages)
    const int lm = (t & 7) * 8;   // 0..56 (m cols this thread stages)
    const float* Kp = K + (size_t)ld * HW + lm;
    const float* Vp = V + (size_t)ld * HW + lm;
    float4 ka = *(const float4*)&Kp[0], kb = *(const float4*)&Kp[4];
    float4 va = *(const float4*)&Vp[0], vb = *(const float4*)&Vp[4];

    for (int m0 = 0; m0 < HW; m0 += 64) {
        __syncthreads();
        *(float4*)&Ks[ld][lm] = ka; *(float4*)&Ks[ld][lm + 4] = kb;
        *(float4*)&Vs[ld][lm] = va; *(float4*)&Vs[ld][lm + 4] = vb;
        __syncthreads();
        if (m0 + 64 < HW) {
            ka = *(const float4*)&Kp[m0 + 64]; kb = *(const float4*)&Kp[m0 + 68];
            va = *(const float4*)&Vp[m0 + 64]; vb = *(const float4*)&Vp[m0 + 68];
        }
        float s = 0.f;
        #pragma unroll
        for (int d = 0; d < 32; d++) s = fmaf(q[d], Ks[d][lane], s);
        float mx = s;
        #pragma unroll
        for (int off = 32; off; off >>= 1) mx = fmaxf(mx, __shfl_xor(mx, off));
        if (mx > M) {  // wave-uniform
            const float corr = __expf(M - mx);
            S *= corr;
            #pragma unroll
            for (int d = 0; d < 32; d++) O[d] *= corr;
            M = mx;
        }
        float p = __expf(s - M);
        float psum = p;
        #pragma unroll
        for (int off = 32; off; off >>= 1) psum += __shfl_xor(psum, off);
        S += psum;
        #pragma unroll
        for (int d = 0; d < 32; d++) O[d] = fmaf(p, Vs[d][lane], O[d]);
    }
    #pragma unroll
    for (int d = 0; d < 32; d++) {
        #pragma unroll
        for (int off = 32; off; off >>= 1) O[d] += __shfl_xor(O[d], off);
    }
    const float inv = 1.f / S;
    float val = 0.f;
    #pragma unroll
    for (int d = 0; d < 32; d++) val = (lane == d) ? O[d] : val;
    if (lane < 32)
        ao[(size_t)j * 128 * HW + (size_t)(lane * 4 + h) * HW + n] = val * inv;
}

extern "C" void kernel_launch(void* const* d_in, const int* in_sizes, int n_in,
                              void* d_out, int out_size, void* d_ws, size_t ws_size,
                              hipStream_t stream)
{
    (void)in_sizes; (void)n_in; (void)out_size; (void)ws_size;
    const float* x      = (const float*)d_in[0];
    const float* cv1_w  = (const float*)d_in[1];
    const float* cv1_g  = (const float*)d_in[2];
    const float* cv1_b  = (const float*)d_in[3];
    const float* cv1_m  = (const float*)d_in[4];
    const float* cv1_v  = (const float*)d_in[5];
    const float* n1_g   = (const float*)d_in[6];
    const float* n1_b   = (const float*)d_in[7];
    const float* qkv_w  = (const float*)d_in[8];
    const float* qkv_b  = (const float*)d_in[9];
    const float* proj_w = (const float*)d_in[10];
    const float* proj_b = (const float*)d_in[11];
    const float* n2_g   = (const float*)d_in[12];
    const float* n2_b   = (const float*)d_in[13];
    const float* f1_w   = (const float*)d_in[14];
    const float* f1_b   = (const float*)d_in[15];
    const float* f2_w   = (const float*)d_in[16];
    const float* f2_b   = (const float*)d_in[17];
    const float* cv2_w  = (const float*)d_in[18];
    const float* cv2_g  = (const float*)d_in[19];
    const float* cv2_b  = (const float*)d_in[20];
    const float* cv2_m  = (const float*)d_in[21];
    const float* cv2_v  = (const float*)d_in[22];
    float* out = (float*)d_out;

    float* ws   = (float*)d_ws;
    float* CAT  = ws;                      // 3 x 512 x HW  (y1|y2|cur1|cur2)
    float* Z    = CAT + 3538944;           // 3 x 128 x HW
    float* QKV  = Z + 884736;              // 3 x 384 x HW
    float* F    = QKV;                     // 3 x 256 x HW (aliases QKV; disjoint lifetime)
    float* AO   = QKV + 2654208;           // 3 x 128 x HW
    float* STAT = AO + 884736;             // 512 floats

    const long sCAT = 512L * HW, sZ = 128L * HW, sQKV = 384L * HW;
    const long sAO = 128L * HW, sF = 256L * HW, sX = 256L * HW, sOUT = 256L * HW;
    dim3 blk(256);

    // conv1 + BN + SiLU -> CAT channels 0..255
    gemm_f32<EPI_BNSILU><<<dim3(36, 4, 3), blk, 0, stream>>>(
        cv1_w, x, CAT, 256, sX, sCAT, cv1_g, cv1_b, cv1_m, cv1_v, nullptr, 0);

    for (int i = 0; i < 2; i++) {
        const long prev = (i == 0) ? 128L : 256L;
        const long next = 256L + 128L * i;

        gn_partial<<<dim3(48, 3), blk, 0, stream>>>(CAT + prev * HW, sCAT, STAT);
        gn_reduce<<<dim3(3), dim3(64), 0, stream>>>(STAT);
        gn_apply<<<dim3(72, 3), blk, 0, stream>>>(CAT + prev * HW, sCAT, Z, sZ,
                                                  n1_g + i * 128, n1_b + i * 128, STAT);
        gemm_f32<EPI_BIAS><<<dim3(36, 6, 3), blk, 0, stream>>>(
            qkv_w + (size_t)i * 384 * 128, Z, QKV, 128, sZ, sQKV,
            qkv_b + i * 384, nullptr, nullptr, nullptr, nullptr, 0);
        flash_attn<<<dim3(576, 12), blk, 0, stream>>>(QKV, AO);
        gemm_f32<EPI_BIAS_RES><<<dim3(36, 2, 3), blk, 0, stream>>>(
            proj_w + (size_t)i * 128 * 128, AO, CAT + next * HW, 128, sAO, sCAT,
            proj_b + i * 128, nullptr, nullptr, nullptr, CAT + prev * HW, sCAT);

        gn_partial<<<dim3(48, 3), blk, 0, stream>>>(CAT + next * HW, sCAT, STAT);
        gn_reduce<<<dim3(3), dim3(64), 0, stream>>>(STAT);
        gn_apply<<<dim3(72, 3), blk, 0, stream>>>(CAT + next * HW, sCAT, Z, sZ,
                                                  n2_g + i * 128, n2_b + i * 128, STAT);
        gemm_f32<EPI_BIAS_GELU><<<dim3(36, 4, 3), blk, 0, stream>>>(
            f1_w + (size_t)i * 256 * 128, Z, F, 128, sZ, sF,
            f1_b + i * 256, nullptr, nullptr, nullptr, nullptr, 0);
        gemm_f32<EPI_BIAS_RES><<<dim3(36, 2, 3), blk, 0, stream>>>(
            f2_w + (size_t)i * 128 * 256, F, CAT + next * HW, 256, sF, sCAT,
            f2_b + i * 128, nullptr, nullptr, nullptr, CAT + next * HW, sCAT);
    }

    // conv2 + BN + SiLU over concat(512ch) -> out
    gemm_f32<EPI_BNSILU><<<dim3(36, 4, 3), blk, 0, stream>>>(
        cv2_w, CAT, out, 512, sCAT, sOUT, cv2_g, cv2_b, cv2_m, cv2_v, nullptr, 0);
}

// Round 2
// 288.846 us; speedup vs baseline: 4.3971x; 4.3971x over previous
//
#include <hip/hip_runtime.h>
#include <math.h>

#define HW 2304
#define EPSV 1e-5f
#define ATT_SCALE 0.17677669529663687f  // 32^-0.5

enum { EPI_BNSILU = 0, EPI_BIAS = 1, EPI_BIAS_GELU = 2, EPI_BIAS_RES = 3, EPI_QKV = 4 };

typedef __attribute__((ext_vector_type(8))) short bf16x8;
typedef __attribute__((ext_vector_type(4))) float f32x4;

static __device__ __forceinline__ ushort f2b(float f) {
    union { float f; unsigned u; } c; c.f = f;
    unsigned r = c.u + 0x7FFF + ((c.u >> 16) & 1);  // RNE
    return (ushort)(r >> 16);
}

// Y[b][o][n] = epi( sum_c W[o][c] * X[b][c][n] )
// 64x64 output tile per block, 256 threads, 4x4 micro-tile, K-tile 16.
// EPI_QKV: writes bf16 to YB (batch0 channels pre-scaled by ATT_SCALE) and,
// for b==1 (K), also writes the transposed bf16 buffer KT[gh][n][d].
template <int EPI>
__global__ __launch_bounds__(256) void gemm_f32(
    const float* __restrict__ W, const float* __restrict__ X,
    float* __restrict__ Y, int C, long sxb, long syb,
    const float* __restrict__ p0, const float* __restrict__ p1,
    const float* __restrict__ p2, const float* __restrict__ p3,
    const float* __restrict__ R, long srb,
    ushort* __restrict__ YB, ushort* __restrict__ KTo)
{
    __shared__ float As[16][68];  // [k][o], padded
    __shared__ float Bs[16][64];  // [k][n]
    const int b  = blockIdx.z;
    const int ob = blockIdx.y * 64;
    const int nb = blockIdx.x * 64;
    const float* Xb = X + (size_t)b * sxb;
    const int t  = threadIdx.x;
    const int tx = t & 15, ty = t >> 4;
    const int wo = t >> 2, wk = (t & 3) * 4;
    const int xk = t >> 4, xn = (t & 15) * 4;

    float acc[4][4] = {};
    float4 wv = *(const float4*)&W[(size_t)(ob + wo) * C + wk];
    float4 xv = *(const float4*)&Xb[(size_t)xk * HW + nb + xn];

    for (int c0 = 0; c0 < C; c0 += 16) {
        __syncthreads();
        As[wk + 0][wo] = wv.x; As[wk + 1][wo] = wv.y;
        As[wk + 2][wo] = wv.z; As[wk + 3][wo] = wv.w;
        *(float4*)&Bs[xk][xn] = xv;
        __syncthreads();
        if (c0 + 16 < C) {
            wv = *(const float4*)&W[(size_t)(ob + wo) * C + c0 + 16 + wk];
            xv = *(const float4*)&Xb[(size_t)(c0 + 16 + xk) * HW + nb + xn];
        }
        #pragma unroll
        for (int k = 0; k < 16; k++) {
            float4 bv4 = *(const float4*)&Bs[k][tx * 4];
            float bj[4] = {bv4.x, bv4.y, bv4.z, bv4.w};
            float ai[4];
            #pragma unroll
            for (int i = 0; i < 4; i++) ai[i] = As[k][ty * 4 + i];
            #pragma unroll
            for (int i = 0; i < 4; i++)
                #pragma unroll
                for (int j = 0; j < 4; j++)
                    acc[i][j] = fmaf(ai[i], bj[j], acc[i][j]);
        }
    }

    if (EPI == EPI_QKV) {
        const float qs = (b == 0) ? ATT_SCALE : 1.f;
        #pragma unroll
        for (int i = 0; i < 4; i++) {
            const int o = ob + ty * 4 + i;
            const float bias = p0[o];
            ushort4 u;
            u.x = f2b((acc[i][0] + bias) * qs);
            u.y = f2b((acc[i][1] + bias) * qs);
            u.z = f2b((acc[i][2] + bias) * qs);
            u.w = f2b((acc[i][3] + bias) * qs);
            *(ushort4*)&YB[(size_t)(b * 384 + o) * HW + nb + tx * 4] = u;
        }
        if (b == 1) {
            const int d0 = (ob + ty * 4) & 31;
            const int gi = (ob + ty * 4) >> 5;  // g*4+h
            const float b0 = p0[ob + ty * 4 + 0], b1 = p0[ob + ty * 4 + 1];
            const float b2 = p0[ob + ty * 4 + 2], b3 = p0[ob + ty * 4 + 3];
            #pragma unroll
            for (int j = 0; j < 4; j++) {
                const int n = nb + tx * 4 + j;
                ushort4 u;
                u.x = f2b(acc[0][j] + b0); u.y = f2b(acc[1][j] + b1);
                u.z = f2b(acc[2][j] + b2); u.w = f2b(acc[3][j] + b3);
                *(ushort4*)&KTo[(size_t)gi * HW * 32 + (size_t)n * 32 + d0] = u;
            }
        }
        return;
    }

    #pragma unroll
    for (int i = 0; i < 4; i++) {
        const int o = ob + ty * 4 + i;
        float scale = 1.f, shift;
        if (EPI == EPI_BNSILU) {
            const float rs = rsqrtf(p3[o] + EPSV);
            scale = p0[o] * rs;
            shift = p1[o] - p2[o] * scale;
        } else {
            shift = p0[o];
        }
        float rv[4];
        if (EPI == EPI_BIAS_RES)
            *(float4*)rv = *(const float4*)&R[(size_t)b * srb + (size_t)o * HW + nb + tx * 4];
        float ov[4];
        #pragma unroll
        for (int j = 0; j < 4; j++) {
            float v = fmaf(acc[i][j], scale, shift);
            if (EPI == EPI_BNSILU)         v = v / (1.f + __expf(-v));
            else if (EPI == EPI_BIAS_GELU) v = 0.5f * v * (1.f + erff(v * 0.70710678f));
            else if (EPI == EPI_BIAS_RES)  v += rv[j];
            ov[j] = v;
        }
        *(float4*)&Y[(size_t)b * syb + (size_t)o * HW + nb + tx * 4] = *(float4*)ov;
    }
}

// GroupNorm(num_groups=1) over 128*HW elems per batch: partial -> reduce -> apply
__global__ __launch_bounds__(256) void gn_partial(
    const float* __restrict__ X, long sxb, float* __restrict__ stats)
{
    const int b = blockIdx.y;
    const float* xb = X + (size_t)b * sxb + (size_t)blockIdx.x * 6144;
    float s = 0.f, sq = 0.f;
    #pragma unroll
    for (int k = 0; k < 6; k++) {
        float4 v = *(const float4*)&xb[(size_t)(k * 256 + threadIdx.x) * 4];
        s  += v.x + v.y + v.z + v.w;
        sq += v.x * v.x + v.y * v.y + v.z * v.z + v.w * v.w;
    }
    #pragma unroll
    for (int off = 32; off; off >>= 1) { s += __shfl_xor(s, off); sq += __shfl_xor(sq, off); }
    __shared__ float ps[4], pq[4];
    const int wave = threadIdx.x >> 6, lane = threadIdx.x & 63;
    if (lane == 0) { ps[wave] = s; pq[wave] = sq; }
    __syncthreads();
    if (threadIdx.x == 0) {
        stats[b * 48 + blockIdx.x]       = ps[0] + ps[1] + ps[2] + ps[3];
        stats[144 + b * 48 + blockIdx.x] = pq[0] + pq[1] + pq[2] + pq[3];
    }
}

__global__ void gn_reduce(float* __restrict__ stats)
{
    const int b = blockIdx.x, t = threadIdx.x;  // 64 threads
    float s  = (t < 48) ? stats[b * 48 + t] : 0.f;
    float sq = (t < 48) ? stats[144 + b * 48 + t] : 0.f;
    #pragma unroll
    for (int off = 32; off; off >>= 1) { s += __shfl_xor(s, off); sq += __shfl_xor(sq, off); }
    if (t == 0) {
        const float inv = 1.f / 294912.f;
        const float mean = s * inv;
        const float var  = sq * inv - mean * mean;
        stats[288 + b] = mean;
        stats[292 + b] = rsqrtf(var + EPSV);
    }
}

__global__ __launch_bounds__(256) void gn_apply(
    const float* __restrict__ X, long sxb, float* __restrict__ Z, long szb,
    const float* __restrict__ g, const float* __restrict__ bb,
    const float* __restrict__ stats)
{
    const int b = blockIdx.y;
    const float mean = stats[288 + b];
    const float rs   = stats[292 + b];
    const float* xb = X + (size_t)b * sxb;
    float* zb = Z + (size_t)b * szb;
    #pragma unroll
    for (int k = 0; k < 4; k++) {
        const int v4 = blockIdx.x * 1024 + k * 256 + threadIdx.x;
        const int c  = v4 / 576;  // HW/4 = 576 float4 per channel
        const float sc = rs * g[c];
        const float sh = bb[c] - mean * sc;
        float4 v = *(const float4*)&xb[(size_t)v4 * 4];
        v.x = fmaf(v.x, sc, sh); v.y = fmaf(v.y, sc, sh);
        v.z = fmaf(v.z, sc, sh); v.w = fmaf(v.w, sc, sh);
        *(float4*)&zb[(size_t)v4 * 4] = v;
    }
}

// MFMA flash attention (bf16 inputs, fp32 accum).
// 12 (g,h) pairs; N=M=2304, D=32. One wave (64 threads) per block, 16 queries.
// Swapped QK^T: ST[m][n] = mfma(A=KT[m][d], B=Q[d][n]); online softmax per
// column n (lanes n, n+16, n+32, n+48); P through per-wave LDS (padded rows);
// PV: OT[d][n] = mfma(A=V[d][m], B=P[m][n]) accumulated over m-tiles.
__global__ __launch_bounds__(64) void attn_mfma(
    const ushort* __restrict__ qkvb,  // [3][384][HW] bf16, Q pre-scaled
    const ushort* __restrict__ ktbuf, // [12][HW][32] bf16
    float* __restrict__ ao)           // [3][128][HW] fp32, channel (d*4+h)
{
    __shared__ __align__(16) ushort plds[16][72];  // [n][m], 72 = pad
    const int gh = blockIdx.y, g = gh >> 2, h = gh & 3;
    const int l = threadIdx.x;
    const int ln = l & 15, lg = l >> 4;
    const int n0 = blockIdx.x * 16;

    const ushort* Q  = qkvb + (size_t)(g * 128 + h * 32) * HW;
    const ushort* V  = qkvb + (size_t)(768 + g * 128 + h * 32) * HW;
    const ushort* KT = ktbuf + (size_t)gh * HW * 32;

    // Q B-frag: lane holds Q[lg*8+e][n0+ln]  (loaded once)
    bf16x8 qf;
    #pragma unroll
    for (int e = 0; e < 8; e++) qf[e] = (short)Q[(size_t)(lg * 8 + e) * HW + n0 + ln];

    f32x4 o0 = {0.f, 0.f, 0.f, 0.f}, o1 = {0.f, 0.f, 0.f, 0.f};
    float M = -3.0e38f, S = 0.f;

    const ushort* ktp = KT + ln * 32 + lg * 8;            // + m*32
    const ushort* vp0 = V + (size_t)ln * HW + lg * 8;     // dt=0, + m
    const ushort* vp1 = V + (size_t)(16 + ln) * HW + lg * 8;

    bf16x8 kf[4], vf[4], kfn[4], vfn[4];
    #pragma unroll
    for (int mc = 0; mc < 4; mc++) kf[mc] = *(const bf16x8*)(ktp + (size_t)(mc * 16) * 32);
    vf[0] = *(const bf16x8*)(vp0 + 0);  vf[1] = *(const bf16x8*)(vp0 + 32);
    vf[2] = *(const bf16x8*)(vp1 + 0);  vf[3] = *(const bf16x8*)(vp1 + 32);

    for (int m0 = 0; m0 < HW; m0 += 64) {
        f32x4 st[4];
        const f32x4 zero = {0.f, 0.f, 0.f, 0.f};
        #pragma unroll
        for (int mc = 0; mc < 4; mc++)
            st[mc] = __builtin_amdgcn_mfma_f32_16x16x32_bf16(kf[mc], qf, zero, 0, 0, 0);

        if (m0 + 64 < HW) {  // prefetch next tile's fragments
            #pragma unroll
            for (int mc = 0; mc < 4; mc++)
                kfn[mc] = *(const bf16x8*)(ktp + (size_t)(m0 + 64 + mc * 16) * 32);
            vfn[0] = *(const bf16x8*)(vp0 + m0 + 64);  vfn[1] = *(const bf16x8*)(vp0 + m0 + 96);
            vfn[2] = *(const bf16x8*)(vp1 + m0 + 64);  vfn[3] = *(const bf16x8*)(vp1 + m0 + 96);
        }

        // online softmax over this tile's 64 rows for column n
        float mx = st[0][0];
        #pragma unroll
        for (int mc = 0; mc < 4; mc++)
            #pragma unroll
            for (int r = 0; r < 4; r++) mx = fmaxf(mx, st[mc][r]);
        mx = fmaxf(mx, __shfl_xor(mx, 16));
        mx = fmaxf(mx, __shfl_xor(mx, 32));
        const float Mn = fmaxf(M, mx);
        const float corr = __expf(M - Mn);
        float ps = 0.f;
        ushort4 pw[4];
        #pragma unroll
        for (int mc = 0; mc < 4; mc++) {
            float p0v = __expf(st[mc][0] - Mn), p1v = __expf(st[mc][1] - Mn);
            float p2v = __expf(st[mc][2] - Mn), p3v = __expf(st[mc][3] - Mn);
            ps += (p0v + p1v) + (p2v + p3v);
            pw[mc].x = f2b(p0v); pw[mc].y = f2b(p1v);
            pw[mc].z = f2b(p2v); pw[mc].w = f2b(p3v);
        }
        ps += __shfl_xor(ps, 16);
        ps += __shfl_xor(ps, 32);
        S = S * corr + ps;
        M = Mn;
        #pragma unroll
        for (int r = 0; r < 4; r++) { o0[r] *= corr; o1[r] *= corr; }

        // P -> LDS (rows = m, padded stride 72), then read B-frags
        #pragma unroll
        for (int mc = 0; mc < 4; mc++)
            *(ushort4*)&plds[ln][mc * 16 + lg * 4] = pw[mc];
        bf16x8 pf0 = *(const bf16x8*)&plds[ln][lg * 8];
        bf16x8 pf1 = *(const bf16x8*)&plds[ln][32 + lg * 8];

        o0 = __builtin_amdgcn_mfma_f32_16x16x32_bf16(vf[0], pf0, o0, 0, 0, 0);
        o0 = __builtin_amdgcn_mfma_f32_16x16x32_bf16(vf[1], pf1, o0, 0, 0, 0);
        o1 = __builtin_amdgcn_mfma_f32_16x16x32_bf16(vf[2], pf0, o1, 0, 0, 0);
        o1 = __builtin_amdgcn_mfma_f32_16x16x32_bf16(vf[3], pf1, o1, 0, 0, 0);

        #pragma unroll
        for (int mc = 0; mc < 4; mc++) { kf[mc] = kfn[mc]; vf[mc] = vfn[mc]; }
    }

    const float inv = 1.f / S;
    #pragma unroll
    for (int r = 0; r < 4; r++) {
        const int d = lg * 4 + r;
        ao[(size_t)g * 128 * HW + (size_t)(d * 4 + h) * HW + n0 + ln] = o0[r] * inv;
        ao[(size_t)g * 128 * HW + (size_t)((d + 16) * 4 + h) * HW + n0 + ln] = o1[r] * inv;
    }
}

extern "C" void kernel_launch(void* const* d_in, const int* in_sizes, int n_in,
                              void* d_out, int out_size, void* d_ws, size_t ws_size,
                              hipStream_t stream)
{
    (void)in_sizes; (void)n_in; (void)out_size; (void)ws_size;
    const float* x      = (const float*)d_in[0];
    const float* cv1_w  = (const float*)d_in[1];
    const float* cv1_g  = (const float*)d_in[2];
    const float* cv1_b  = (const float*)d_in[3];
    const float* cv1_m  = (const float*)d_in[4];
    const float* cv1_v  = (const float*)d_in[5];
    const float* n1_g   = (const float*)d_in[6];
    const float* n1_b   = (const float*)d_in[7];
    const float* qkv_w  = (const float*)d_in[8];
    const float* qkv_b  = (const float*)d_in[9];
    const float* proj_w = (const float*)d_in[10];
    const float* proj_b = (const float*)d_in[11];
    const float* n2_g   = (const float*)d_in[12];
    const float* n2_b   = (const float*)d_in[13];
    const float* f1_w   = (const float*)d_in[14];
    const float* f1_b   = (const float*)d_in[15];
    const float* f2_w   = (const float*)d_in[16];
    const float* f2_b   = (const float*)d_in[17];
    const float* cv2_w  = (const float*)d_in[18];
    const float* cv2_g  = (const float*)d_in[19];
    const float* cv2_b  = (const float*)d_in[20];
    const float* cv2_m  = (const float*)d_in[21];
    const float* cv2_v  = (const float*)d_in[22];
    float* out = (float*)d_out;

    float* ws   = (float*)d_ws;
    float* CAT  = ws;                      // 3 x 512 x HW
    float* Z    = CAT + 3538944;           // 3 x 128 x HW
    float* RG   = Z + 884736;              // region: QKVb+KT bf16  OR  F fp32
    ushort* QKVb = (ushort*)RG;            // 3 x 384 x HW bf16
    ushort* KTb  = (ushort*)(RG + 1327104);// 12 x HW x 32 bf16
    float* F    = RG;                      // 3 x 256 x HW fp32 (disjoint lifetime)
    float* AO   = RG + 2654208;            // 3 x 128 x HW fp32
    float* STAT = AO + 884736;             // 512 floats

    const long sCAT = 512L * HW, sZ = 128L * HW;
    const long sAO = 128L * HW, sF = 256L * HW, sX = 256L * HW, sOUT = 256L * HW;
    dim3 blk(256);

    // conv1 + BN + SiLU -> CAT channels 0..255
    gemm_f32<EPI_BNSILU><<<dim3(36, 4, 3), blk, 0, stream>>>(
        cv1_w, x, CAT, 256, sX, sCAT, cv1_g, cv1_b, cv1_m, cv1_v, nullptr, 0,
        nullptr, nullptr);

    for (int i = 0; i < 2; i++) {
        const long prev = (i == 0) ? 128L : 256L;
        const long next = 256L + 128L * i;

        gn_partial<<<dim3(48, 3), blk, 0, stream>>>(CAT + prev * HW, sCAT, STAT);
        gn_reduce<<<dim3(3), dim3(64), 0, stream>>>(STAT);
        gn_apply<<<dim3(72, 3), blk, 0, stream>>>(CAT + prev * HW, sCAT, Z, sZ,
                                                  n1_g + i * 128, n1_b + i * 128, STAT);
        gemm_f32<EPI_QKV><<<dim3(36, 6, 3), blk, 0, stream>>>(
            qkv_w + (size_t)i * 384 * 128, Z, nullptr, 128, sZ, 0,
            qkv_b + i * 384, nullptr, nullptr, nullptr, nullptr, 0,
            QKVb, KTb);
        attn_mfma<<<dim3(144, 12), dim3(64), 0, stream>>>(QKVb, KTb, AO);
        gemm_f32<EPI_BIAS_RES><<<dim3(36, 2, 3), blk, 0, stream>>>(
            proj_w + (size_t)i * 128 * 128, AO, CAT + next * HW, 128, sAO, sCAT,
            proj_b + i * 128, nullptr, nullptr, nullptr, CAT + prev * HW, sCAT,
            nullptr, nullptr);

        gn_partial<<<dim3(48, 3), blk, 0, stream>>>(CAT + next * HW, sCAT, STAT);
        gn_reduce<<<dim3(3), dim3(64), 0, stream>>>(STAT);
        gn_apply<<<dim3(72, 3), blk, 0, stream>>>(CAT + next * HW, sCAT, Z, sZ,
                                                  n2_g + i * 128, n2_b + i * 128, STAT);
        gemm_f32<EPI_BIAS_GELU><<<dim3(36, 4, 3), blk, 0, stream>>>(
            f1_w + (size_t)i * 256 * 128, Z, F, 128, sZ, sF,
            f1_b + i * 256, nullptr, nullptr, nullptr, nullptr, 0,
            nullptr, nullptr);
        gemm_f32<EPI_BIAS_RES><<<dim3(36, 2, 3), blk, 0, stream>>>(
            f2_w + (size_t)i * 128 * 256, F, CAT + next * HW, 256, sF, sCAT,
            f2_b + i * 128, nullptr, nullptr, nullptr, CAT + next * HW, sCAT,
            nullptr, nullptr);
    }

    // conv2 + BN + SiLU over concat(512ch) -> out
    gemm_f32<EPI_BNSILU><<<dim3(36, 4, 3), blk, 0, stream>>>(
        cv2_w, CAT, out, 512, sCAT, sOUT, cv2_g, cv2_b, cv2_m, cv2_v, nullptr, 0,
        nullptr, nullptr);
}